// Round 1
// baseline (12704.701 us; speedup 1.0000x reference)
//
#include <hip/hip_runtime.h>
#include <stdint.h>
#include <stddef.h>

typedef _Float16 f16;
typedef __attribute__((ext_vector_type(8))) _Float16 f16x8;
typedef __attribute__((ext_vector_type(4))) _Float16 f16x4;
typedef __attribute__((ext_vector_type(4))) float     f32x4;

#define NB 8
#define NS 2048
#define NHID 1024
#define NWG 64

__device__ __forceinline__ float fsig(float x)  { return 1.f/(1.f+__expf(-x)); }
__device__ __forceinline__ float fsilu(float x) { return x/(1.f+__expf(-x)); }

// ---------------------------------------------------------------- pre-kernels
__global__ __launch_bounds__(256) void k_cvt_f16(const float* __restrict__ in,
                                                 f16* __restrict__ out, int n) {
  int i = (blockIdx.x*blockDim.x + threadIdx.x)*4;
  int stride = gridDim.x*blockDim.x*4;
  for (; i < n; i += stride) {
    f32x4 v = *(const f32x4*)(in + i);
    f16x4 o = { (f16)v[0], (f16)v[1], (f16)v[2], (f16)v[3] };
    *(f16x4*)(out + i) = o;
  }
}

// W [K][N] f32 -> Wt [N][K] f16
__global__ __launch_bounds__(256) void k_transpose_cvt(const float* __restrict__ W,
                                                       f16* __restrict__ Wt,
                                                       int K, int N) {
  __shared__ float tile[32][33];
  int k0 = blockIdx.x*32, n0 = blockIdx.y*32;
  int tx = threadIdx.x & 31, ty = threadIdx.x >> 5;
  for (int i = ty; i < 32; i += 8) tile[i][tx] = W[(size_t)(k0+i)*N + n0 + tx];
  __syncthreads();
  for (int i = ty; i < 32; i += 8) Wt[(size_t)(n0+i)*K + k0 + tx] = (f16)tile[tx][i];
}

// ---------------------------------------------------------------- GEMM 1: z = silu(xW_u)*silu(xW_v)+xW_w
// A = x_f16 [16384][1024] ; Bt = Wt_in [3072][1024] (row n = original col, K contiguous)
__global__ __launch_bounds__(256) void k_gemm1(const f16* __restrict__ A,
                                               const f16* __restrict__ Bt,
                                               const float* __restrict__ b_in,
                                               f16* __restrict__ z) {
  __shared__ f16 As[2][128*64];
  __shared__ f16 Bs[2][3][32*64];
  const int tid  = threadIdx.x;
  const int row0 = blockIdx.x * 128;
  const int j0   = blockIdx.y * 32;
  const int lane = tid & 63, wave = tid >> 6;
  const int wm = wave >> 1, wj = wave & 1;

  f32x4 acc[4][3];
  const f32x4 zv = {0.f,0.f,0.f,0.f};
#pragma unroll
  for (int m = 0; m < 4; ++m)
#pragma unroll
    for (int s = 0; s < 3; ++s) acc[m][s] = zv;

  f16x8 ar[4]; f16x8 br[3];

  auto loadT = [&](int kt) {
    int k0 = kt*64;
#pragma unroll
    for (int i = 0; i < 4; ++i) {
      int c = tid + i*256; int r = c >> 3;
      ar[i] = *(const f16x8*)(A + (size_t)(row0 + r)*1024 + k0 + (c & 7)*8);
    }
#pragma unroll
    for (int i = 0; i < 3; ++i) {
      int c = tid + i*256; int strip = c >> 8; int cc = c & 255; int r = cc >> 3;
      br[i] = *(const f16x8*)(Bt + (size_t)(strip*1024 + j0 + r)*1024 + k0 + (cc & 7)*8);
    }
  };
  auto writeT = [&](int buf) {
#pragma unroll
    for (int i = 0; i < 4; ++i) {
      int c = tid + i*256; int r = c >> 3; int kb = (c & 7)*16;
      *(f16x8*)((char*)As[buf] + r*128 + (kb ^ ((r & 7) << 4))) = ar[i];
    }
#pragma unroll
    for (int i = 0; i < 3; ++i) {
      int c = tid + i*256; int strip = c >> 8; int cc = c & 255; int r = cc >> 3; int kb = (cc & 7)*16;
      *(f16x8*)((char*)Bs[buf][strip] + r*128 + (kb ^ ((r & 7) << 4))) = br[i];
    }
  };
  auto compute = [&](int buf) {
    const char* Ab = (const char*)As[buf];
#pragma unroll
    for (int kk = 0; kk < 2; ++kk) {
      int kq = kk*64 + ((lane >> 4) << 4);
      f16x8 af[4];
#pragma unroll
      for (int mt = 0; mt < 4; ++mt) {
        int r = wm*64 + mt*16 + (lane & 15);
        af[mt] = *(const f16x8*)(Ab + r*128 + (kq ^ ((r & 7) << 4)));
      }
#pragma unroll
      for (int st = 0; st < 3; ++st) {
        int cB = wj*16 + (lane & 15);
        f16x8 bf = *(const f16x8*)((const char*)Bs[buf][st] + cB*128 + (kq ^ ((cB & 7) << 4)));
#pragma unroll
        for (int mt = 0; mt < 4; ++mt)
          acc[mt][st] = __builtin_amdgcn_mfma_f32_16x16x32_f16(af[mt], bf, acc[mt][st], 0, 0, 0);
      }
    }
  };

  loadT(0); writeT(0);
  __syncthreads();
  for (int kt = 0; kt < 16; ++kt) {
    int cur = kt & 1;
    if (kt + 1 < 16) loadT(kt+1);
    compute(cur);
    if (kt + 1 < 16) writeT(cur ^ 1);
    __syncthreads();
  }

  const int jc = j0 + wj*16 + (lane & 15);
  const float bu = b_in[jc], bv = b_in[1024 + jc], bw = b_in[2048 + jc];
#pragma unroll
  for (int mt = 0; mt < 4; ++mt) {
#pragma unroll
    for (int i = 0; i < 4; ++i) {
      int r = row0 + wm*64 + mt*16 + ((lane >> 4) << 2) + i;
      float u = acc[mt][0][i] + bu;
      float v = acc[mt][1][i] + bv;
      float w = acc[mt][2][i] + bw;
      float zz = fsilu(u)*fsilu(v) + w;
      int b_ = r >> 11, s_ = r & 2047;
      z[(((size_t)s_*64 + (jc >> 4))*8 + b_)*16 + (jc & 15)] = (f16)zz;
    }
  }
}

// ---------------------------------------------------------------- GEMM 3: out = hiddens @ W_out + b_out
// A = hid [16384][1024] (row = s*8+b) ; Bt = Wt_out [1024][1024]
__global__ __launch_bounds__(256) void k_gemm3(const f16* __restrict__ A,
                                               const f16* __restrict__ Bt,
                                               const float* __restrict__ b_out,
                                               float* __restrict__ out) {
  __shared__ f16 As[2][128*64];
  __shared__ f16 Bs[2][32*64];
  const int tid  = threadIdx.x;
  const int row0 = blockIdx.x * 128;
  const int n0   = blockIdx.y * 32;
  const int lane = tid & 63, wave = tid >> 6;
  const int wm = wave >> 1, wn = wave & 1;

  f32x4 acc[4];
  const f32x4 zv = {0.f,0.f,0.f,0.f};
#pragma unroll
  for (int m = 0; m < 4; ++m) acc[m] = zv;

  f16x8 ar[4]; f16x8 br1;

  auto loadT = [&](int kt) {
    int k0 = kt*64;
#pragma unroll
    for (int i = 0; i < 4; ++i) {
      int c = tid + i*256; int r = c >> 3;
      ar[i] = *(const f16x8*)(A + (size_t)(row0 + r)*1024 + k0 + (c & 7)*8);
    }
    { int c = tid; int r = c >> 3;
      br1 = *(const f16x8*)(Bt + (size_t)(n0 + r)*1024 + k0 + (c & 7)*8); }
  };
  auto writeT = [&](int buf) {
#pragma unroll
    for (int i = 0; i < 4; ++i) {
      int c = tid + i*256; int r = c >> 3; int kb = (c & 7)*16;
      *(f16x8*)((char*)As[buf] + r*128 + (kb ^ ((r & 7) << 4))) = ar[i];
    }
    { int c = tid; int r = c >> 3; int kb = (c & 7)*16;
      *(f16x8*)((char*)Bs[buf] + r*128 + (kb ^ ((r & 7) << 4))) = br1; }
  };
  auto compute = [&](int buf) {
    const char* Ab = (const char*)As[buf];
#pragma unroll
    for (int kk = 0; kk < 2; ++kk) {
      int kq = kk*64 + ((lane >> 4) << 4);
      int cB = wn*16 + (lane & 15);
      f16x8 bf = *(const f16x8*)((const char*)Bs[buf] + cB*128 + (kq ^ ((cB & 7) << 4)));
#pragma unroll
      for (int mt = 0; mt < 4; ++mt) {
        int r = wm*64 + mt*16 + (lane & 15);
        f16x8 af = *(const f16x8*)(Ab + r*128 + (kq ^ ((r & 7) << 4)));
        acc[mt] = __builtin_amdgcn_mfma_f32_16x16x32_f16(af, bf, acc[mt], 0, 0, 0);
      }
    }
  };

  loadT(0); writeT(0);
  __syncthreads();
  for (int kt = 0; kt < 16; ++kt) {
    int cur = kt & 1;
    if (kt + 1 < 16) loadT(kt+1);
    compute(cur);
    if (kt + 1 < 16) writeT(cur ^ 1);
    __syncthreads();
  }

  const int n = n0 + wn*16 + (lane & 15);
  const float bo = b_out[n];
#pragma unroll
  for (int mt = 0; mt < 4; ++mt) {
#pragma unroll
    for (int i = 0; i < 4; ++i) {
      int r = row0 + wm*64 + mt*16 + ((lane >> 4) << 2) + i;
      int s = r >> 3, b = r & 7;
      out[(size_t)b*(NS*NHID) + (size_t)s*NHID + n] = acc[mt][i] + bo;
    }
  }
}

// ---------------------------------------------------------------- sequential scan
// 64 persistent WGs; WG w owns H-cols [16w,16w+16); entire fused weight matrix LDS-resident.
#define SCAN_LDS 154880
__global__ __launch_bounds__(256, 1) void k_scan(
    const float* __restrict__ h0g,  const float* __restrict__ Wg,
    const float* __restrict__ bg,   const float* __restrict__ Wr,
    const float* __restrict__ brv,  const float* __restrict__ lng_g,
    const float* __restrict__ lnb_g,const f16* __restrict__ z,
    f16* __restrict__ hid,          float* __restrict__ nhb,
    unsigned* __restrict__ flags,   float* __restrict__ finalh) {
  extern __shared__ char smem[];
  f16*   Wlds = (f16*)smem;                 // 48 cols x 1048 (K-contig, padded stride)
  f16*   hlds = (f16*)(smem + 100608);      // 16 rows x 1048 (rows 8..15 zero)
  float* red  = (float*)(smem + 134144);    // 4 waves x 3 tiles x 64 lanes x 4
  float* lng  = (float*)(smem + 146432);
  float* lnb  = (float*)(smem + 150528);
  float* bia  = (float*)(smem + 154624);

  const int tid  = threadIdx.x;
  const int wg   = blockIdx.x;
  const int wave = tid >> 6, lane = tid & 63;
  const int r8   = tid >> 5, g32 = tid & 31;   // LN: 8 rows x 32 lanes
  const int rr   = (tid >> 4) & 7, cc = tid & 15; // 128-thread (row,col) ops

  // ---- setup: weights -> LDS fp16 (one-time)
  for (int i = tid; i < 48*1024; i += 256) {
    int c = i >> 10, k = i & 1023;
    float wv;
    if (c < 16)      wv = Wg[(size_t)k*2048 + wg*16 + c];
    else if (c < 32) wv = Wg[(size_t)k*2048 + 1024 + wg*16 + (c-16)];
    else             wv = Wr[(size_t)k*1024 + wg*16 + (c-32)];
    Wlds[c*1048 + k] = (f16)wv;
  }
  for (int i = tid; i < 1024; i += 256) { lng[i] = lng_g[i]; lnb[i] = lnb_g[i]; }
  if (tid < 48)
    bia[tid] = (tid < 16) ? bg[wg*16 + tid]
             : (tid < 32) ? bg[1024 + wg*16 + (tid-16)]
                          : brv[wg*16 + (tid-32)];
  for (int i = tid; i < 8*1048; i += 256) hlds[8*1048 + i] = (f16)0.f;
  __syncthreads();

  for (int t = 0; t <= NS; ++t) {
    // prefetch this step's z slice (independent of other WGs)
    f16 zreg = (f16)0.f;
    if (t < NS && tid < 128) zreg = z[(((size_t)t*64 + wg)*8 + rr)*16 + cc];

    if (t > 0) {
      if (tid < 64) {
        while (__hip_atomic_load(&flags[tid], __ATOMIC_RELAXED, __HIP_MEMORY_SCOPE_AGENT) < (unsigned)t)
          __builtin_amdgcn_s_sleep(1);
      }
      __syncthreads();
    }

    // ---- Phase A: h_t -> hlds (fp16), redundant LN per WG
    if (t == 0) {
#pragma unroll
      for (int i = 0; i < 8; ++i) {
        f32x4 v = *(const f32x4*)(h0g + r8*1024 + (i*32 + g32)*4);
        int colb = i*128 + g32*4;
        f16x4 hv = { (f16)v[0], (f16)v[1], (f16)v[2], (f16)v[3] };
        *(f16x4*)(hlds + r8*1048 + colb) = hv;
      }
    } else {
      const float* src = nhb + ((t-1) & 1)*(8*1024) + r8*1024;
      float vals[8][4];
      float sum = 0.f, sq = 0.f;
#pragma unroll
      for (int i = 0; i < 8; ++i) {
#pragma unroll
        for (int e = 0; e < 4; ++e) {
          float v = __hip_atomic_load(src + (i*32 + g32)*4 + e, __ATOMIC_RELAXED, __HIP_MEMORY_SCOPE_AGENT);
          vals[i][e] = v; sum += v; sq += v*v;
        }
      }
#pragma unroll
      for (int off = 16; off > 0; off >>= 1) {
        sum += __shfl_xor(sum, off, 32);
        sq  += __shfl_xor(sq,  off, 32);
      }
      float m  = sum * (1.f/1024.f);
      float va = sq  * (1.f/1024.f) - m*m;
      float rs = rsqrtf(va + 1e-5f);
#pragma unroll
      for (int i = 0; i < 8; ++i) {
        int colb = i*128 + g32*4;
        f16x4 hv;
#pragma unroll
        for (int e = 0; e < 4; ++e)
          hv[e] = (f16)((vals[i][e] - m)*rs*lng[colb+e] + lnb[colb+e]);
        *(f16x4*)(hlds + r8*1048 + colb) = hv;
      }
    }
    __syncthreads();

    // owner writes hiddens[t-1] (= post-LN h_t); epilogue also writes final hidden
    if (t >= 1 && tid < 128) {
      int col = wg*16 + cc;
      f16 hv = hlds[rr*1048 + col];
      hid[((size_t)(t-1)*8 + rr)*1024 + col] = hv;
      if (t == NS) finalh[rr*1024 + col] = (float)hv;
    }
    if (t == NS) break;

    // ---- Phase B: [16x1024]x[1024x48] via MFMA, K split over 4 waves
    f32x4 acc0 = {0,0,0,0}, acc1 = {0,0,0,0}, acc2 = {0,0,0,0};
    {
      const char* hb = (const char*)hlds + (lane & 15)*2096;
      const char* w0 = (const char*)Wlds + ((lane & 15))*2096;
      const char* w1 = (const char*)Wlds + (16 + (lane & 15))*2096;
      const char* w2 = (const char*)Wlds + (32 + (lane & 15))*2096;
      int kbase = wave*256 + ((lane >> 4) << 3);
#pragma unroll
      for (int ks = 0; ks < 8; ++ks) {
        int kb = (kbase + ks*32) * 2;
        f16x8 af = *(const f16x8*)(hb + kb);
        f16x8 b0 = *(const f16x8*)(w0 + kb);
        f16x8 b1 = *(const f16x8*)(w1 + kb);
        f16x8 b2 = *(const f16x8*)(w2 + kb);
        acc0 = __builtin_amdgcn_mfma_f32_16x16x32_f16(af, b0, acc0, 0, 0, 0);
        acc1 = __builtin_amdgcn_mfma_f32_16x16x32_f16(af, b1, acc1, 0, 0, 0);
        acc2 = __builtin_amdgcn_mfma_f32_16x16x32_f16(af, b2, acc2, 0, 0, 0);
      }
    }
    *(f32x4*)(red + ((wave*3 + 0)*64 + lane)*4) = acc0;
    *(f32x4*)(red + ((wave*3 + 1)*64 + lane)*4) = acc1;
    *(f32x4*)(red + ((wave*3 + 2)*64 + lane)*4) = acc2;
    __syncthreads();

    // ---- Phase C: cross-wave reduce + gate math + publish slice
    if (tid < 128) {
      int li  = ((rr >> 2) << 4) + cc;
      int reg = rr & 3;
      float s0 = 0.f, s1 = 0.f, s2 = 0.f;
#pragma unroll
      for (int q = 0; q < 4; ++q) {
        s0 += red[((q*3 + 0)*64 + li)*4 + reg];
        s1 += red[((q*3 + 1)*64 + li)*4 + reg];
        s2 += red[((q*3 + 2)*64 + li)*4 + reg];
      }
      float gv = s0 + bia[cc];
      float gt = s1 + bia[16 + cc];
      float rc = s2 + bia[32 + cc];
      float gate = fsig(gv) * fsilu(gt);
      float nh   = gate*rc + (1.f - gate)*(float)zreg;
      __hip_atomic_store(nhb + (t & 1)*(8*1024) + rr*1024 + wg*16 + cc, nh,
                         __ATOMIC_RELAXED, __HIP_MEMORY_SCOPE_AGENT);
    }
    __syncthreads();  // vmcnt(0): all slice stores complete at LLC before flag
    if (tid == 0)
      __hip_atomic_store(&flags[wg], (unsigned)(t+1), __ATOMIC_RELEASE, __HIP_MEMORY_SCOPE_AGENT);
  }
}

// ---------------------------------------------------------------- launcher
extern "C" void kernel_launch(void* const* d_in, const int* in_sizes, int n_in,
                              void* d_out, int out_size, void* d_ws, size_t ws_size,
                              hipStream_t stream) {
  const float* x      = (const float*)d_in[0];
  const float* h0     = (const float*)d_in[1];
  const float* W_in   = (const float*)d_in[2];
  const float* b_in   = (const float*)d_in[3];
  const float* W_rec  = (const float*)d_in[4];
  const float* b_rec  = (const float*)d_in[5];
  const float* W_gate = (const float*)d_in[6];
  const float* b_gate = (const float*)d_in[7];
  const float* W_out  = (const float*)d_in[8];
  const float* b_out  = (const float*)d_in[9];
  const float* ln_g   = (const float*)d_in[10];
  const float* ln_b   = (const float*)d_in[11];
  float* out = (float*)d_out;

  char* ws = (char*)d_ws;
  f16*   x_f16  = (f16*)(ws);                         // 33,554,432 B
  f16*   Wt_in  = (f16*)(ws + 33554432);              //  6,291,456 B
  f16*   Wt_out = (f16*)(ws + 39845888);              //  2,097,152 B
  f16*   z      = (f16*)(ws + 41943040);              // 33,554,432 B
  f16*   hid    = (f16*)(ws + 75497472);              // 33,554,432 B
  float* nhbuf  = (float*)(ws + 109051904);           //     65,536 B
  unsigned* flg = (unsigned*)(ws + 109117440);        //        256 B

  hipMemsetAsync(flg, 0, 256, stream);

  k_cvt_f16<<<2048, 256, 0, stream>>>(x, x_f16, NB*NS*NHID);
  { dim3 g(32, 96); k_transpose_cvt<<<g, 256, 0, stream>>>(W_in,  Wt_in,  1024, 3072); }
  { dim3 g(32, 32); k_transpose_cvt<<<g, 256, 0, stream>>>(W_out, Wt_out, 1024, 1024); }

  { dim3 g(128, 32); k_gemm1<<<g, 256, 0, stream>>>(x_f16, Wt_in, b_in, z); }

  hipFuncSetAttribute((const void*)k_scan, hipFuncAttributeMaxDynamicSharedMemorySize, SCAN_LDS);
  k_scan<<<NWG, 256, SCAN_LDS, stream>>>(h0, W_gate, b_gate, W_rec, b_rec,
                                         ln_g, ln_b, z, hid, nhbuf, flg,
                                         out + (size_t)NB*NS*NHID);

  { dim3 g(128, 32); k_gemm3<<<g, 256, 0, stream>>>(hid, Wt_out, b_out, out); }
}

// Round 2
// 9416.892 us; speedup vs baseline: 1.3491x; 1.3491x over previous
//
#include <hip/hip_runtime.h>
#include <stdint.h>
#include <stddef.h>

typedef _Float16 f16;
typedef __attribute__((ext_vector_type(8))) _Float16 f16x8;
typedef __attribute__((ext_vector_type(4))) _Float16 f16x4;
typedef __attribute__((ext_vector_type(4))) float     f32x4;
typedef unsigned long long u64;

#define NB 8
#define NS 2048
#define NHID 1024
#define NWG 64

__device__ __forceinline__ float fsig(float x)  { return 1.f/(1.f+__expf(-x)); }
__device__ __forceinline__ float fsilu(float x) { return x/(1.f+__expf(-x)); }

// ---------------------------------------------------------------- pre-kernels
__global__ __launch_bounds__(256) void k_cvt_f16(const float* __restrict__ in,
                                                 f16* __restrict__ out, int n) {
  int i = (blockIdx.x*blockDim.x + threadIdx.x)*4;
  int stride = gridDim.x*blockDim.x*4;
  for (; i < n; i += stride) {
    f32x4 v = *(const f32x4*)(in + i);
    f16x4 o = { (f16)v[0], (f16)v[1], (f16)v[2], (f16)v[3] };
    *(f16x4*)(out + i) = o;
  }
}

// W [K][N] f32 -> Wt [N][K] f16
__global__ __launch_bounds__(256) void k_transpose_cvt(const float* __restrict__ W,
                                                       f16* __restrict__ Wt,
                                                       int K, int N) {
  __shared__ float tile[32][33];
  int k0 = blockIdx.x*32, n0 = blockIdx.y*32;
  int tx = threadIdx.x & 31, ty = threadIdx.x >> 5;
  for (int i = ty; i < 32; i += 8) tile[i][tx] = W[(size_t)(k0+i)*N + n0 + tx];
  __syncthreads();
  for (int i = ty; i < 32; i += 8) Wt[(size_t)(n0+i)*K + k0 + tx] = (f16)tile[tx][i];
}

// ---------------------------------------------------------------- GEMM 1: z = silu(xW_u)*silu(xW_v)+xW_w
__global__ __launch_bounds__(256) void k_gemm1(const f16* __restrict__ A,
                                               const f16* __restrict__ Bt,
                                               const float* __restrict__ b_in,
                                               f16* __restrict__ z) {
  __shared__ f16 As[2][128*64];
  __shared__ f16 Bs[2][3][32*64];
  const int tid  = threadIdx.x;
  const int row0 = blockIdx.x * 128;
  const int j0   = blockIdx.y * 32;
  const int lane = tid & 63, wave = tid >> 6;
  const int wm = wave >> 1, wj = wave & 1;

  f32x4 acc[4][3];
  const f32x4 zv = {0.f,0.f,0.f,0.f};
#pragma unroll
  for (int m = 0; m < 4; ++m)
#pragma unroll
    for (int s = 0; s < 3; ++s) acc[m][s] = zv;

  f16x8 ar[4]; f16x8 br[3];

  auto loadT = [&](int kt) {
    int k0 = kt*64;
#pragma unroll
    for (int i = 0; i < 4; ++i) {
      int c = tid + i*256; int r = c >> 3;
      ar[i] = *(const f16x8*)(A + (size_t)(row0 + r)*1024 + k0 + (c & 7)*8);
    }
#pragma unroll
    for (int i = 0; i < 3; ++i) {
      int c = tid + i*256; int strip = c >> 8; int cc = c & 255; int r = cc >> 3;
      br[i] = *(const f16x8*)(Bt + (size_t)(strip*1024 + j0 + r)*1024 + k0 + (cc & 7)*8);
    }
  };
  auto writeT = [&](int buf) {
#pragma unroll
    for (int i = 0; i < 4; ++i) {
      int c = tid + i*256; int r = c >> 3; int kb = (c & 7)*16;
      *(f16x8*)((char*)As[buf] + r*128 + (kb ^ ((r & 7) << 4))) = ar[i];
    }
#pragma unroll
    for (int i = 0; i < 3; ++i) {
      int c = tid + i*256; int strip = c >> 8; int cc = c & 255; int r = cc >> 3; int kb = (cc & 7)*16;
      *(f16x8*)((char*)Bs[buf][strip] + r*128 + (kb ^ ((r & 7) << 4))) = br[i];
    }
  };
  auto compute = [&](int buf) {
    const char* Ab = (const char*)As[buf];
#pragma unroll
    for (int kk = 0; kk < 2; ++kk) {
      int kq = kk*64 + ((lane >> 4) << 4);
      f16x8 af[4];
#pragma unroll
      for (int mt = 0; mt < 4; ++mt) {
        int r = wm*64 + mt*16 + (lane & 15);
        af[mt] = *(const f16x8*)(Ab + r*128 + (kq ^ ((r & 7) << 4)));
      }
#pragma unroll
      for (int st = 0; st < 3; ++st) {
        int cB = wj*16 + (lane & 15);
        f16x8 bf = *(const f16x8*)((const char*)Bs[buf][st] + cB*128 + (kq ^ ((cB & 7) << 4)));
#pragma unroll
        for (int mt = 0; mt < 4; ++mt)
          acc[mt][st] = __builtin_amdgcn_mfma_f32_16x16x32_f16(af[mt], bf, acc[mt][st], 0, 0, 0);
      }
    }
  };

  loadT(0); writeT(0);
  __syncthreads();
  for (int kt = 0; kt < 16; ++kt) {
    int cur = kt & 1;
    if (kt + 1 < 16) loadT(kt+1);
    compute(cur);
    if (kt + 1 < 16) writeT(cur ^ 1);
    __syncthreads();
  }

  const int jc = j0 + wj*16 + (lane & 15);
  const float bu = b_in[jc], bv = b_in[1024 + jc], bw = b_in[2048 + jc];
#pragma unroll
  for (int mt = 0; mt < 4; ++mt) {
#pragma unroll
    for (int i = 0; i < 4; ++i) {
      int r = row0 + wm*64 + mt*16 + ((lane >> 4) << 2) + i;
      float u = acc[mt][0][i] + bu;
      float v = acc[mt][1][i] + bv;
      float w = acc[mt][2][i] + bw;
      float zz = fsilu(u)*fsilu(v) + w;
      int b_ = r >> 11, s_ = r & 2047;
      z[(((size_t)s_*64 + (jc >> 4))*8 + b_)*16 + (jc & 15)] = (f16)zz;
    }
  }
}

// ---------------------------------------------------------------- GEMM 3: out = hiddens @ W_out + b_out
__global__ __launch_bounds__(256) void k_gemm3(const f16* __restrict__ A,
                                               const f16* __restrict__ Bt,
                                               const float* __restrict__ b_out,
                                               float* __restrict__ out) {
  __shared__ f16 As[2][128*64];
  __shared__ f16 Bs[2][32*64];
  const int tid  = threadIdx.x;
  const int row0 = blockIdx.x * 128;
  const int n0   = blockIdx.y * 32;
  const int lane = tid & 63, wave = tid >> 6;
  const int wm = wave >> 1, wn = wave & 1;

  f32x4 acc[4];
  const f32x4 zv = {0.f,0.f,0.f,0.f};
#pragma unroll
  for (int m = 0; m < 4; ++m) acc[m] = zv;

  f16x8 ar[4]; f16x8 br1;

  auto loadT = [&](int kt) {
    int k0 = kt*64;
#pragma unroll
    for (int i = 0; i < 4; ++i) {
      int c = tid + i*256; int r = c >> 3;
      ar[i] = *(const f16x8*)(A + (size_t)(row0 + r)*1024 + k0 + (c & 7)*8);
    }
    { int c = tid; int r = c >> 3;
      br1 = *(const f16x8*)(Bt + (size_t)(n0 + r)*1024 + k0 + (c & 7)*8); }
  };
  auto writeT = [&](int buf) {
#pragma unroll
    for (int i = 0; i < 4; ++i) {
      int c = tid + i*256; int r = c >> 3; int kb = (c & 7)*16;
      *(f16x8*)((char*)As[buf] + r*128 + (kb ^ ((r & 7) << 4))) = ar[i];
    }
    { int c = tid; int r = c >> 3; int kb = (c & 7)*16;
      *(f16x8*)((char*)Bs[buf] + r*128 + (kb ^ ((r & 7) << 4))) = br1; }
  };
  auto compute = [&](int buf) {
    const char* Ab = (const char*)As[buf];
#pragma unroll
    for (int kk = 0; kk < 2; ++kk) {
      int kq = kk*64 + ((lane >> 4) << 4);
      int cB = wn*16 + (lane & 15);
      f16x8 bf = *(const f16x8*)((const char*)Bs[buf] + cB*128 + (kq ^ ((cB & 7) << 4)));
#pragma unroll
      for (int mt = 0; mt < 4; ++mt) {
        int r = wm*64 + mt*16 + (lane & 15);
        f16x8 af = *(const f16x8*)(Ab + r*128 + (kq ^ ((r & 7) << 4)));
        acc[mt] = __builtin_amdgcn_mfma_f32_16x16x32_f16(af, bf, acc[mt], 0, 0, 0);
      }
    }
  };

  loadT(0); writeT(0);
  __syncthreads();
  for (int kt = 0; kt < 16; ++kt) {
    int cur = kt & 1;
    if (kt + 1 < 16) loadT(kt+1);
    compute(cur);
    if (kt + 1 < 16) writeT(cur ^ 1);
    __syncthreads();
  }

  const int n = n0 + wn*16 + (lane & 15);
  const float bo = b_out[n];
#pragma unroll
  for (int mt = 0; mt < 4; ++mt) {
#pragma unroll
    for (int i = 0; i < 4; ++i) {
      int r = row0 + wm*64 + mt*16 + ((lane >> 4) << 2) + i;
      int s = r >> 3, b = r & 7;
      out[(size_t)b*(NS*NHID) + (size_t)s*NHID + n] = acc[mt][i] + bo;
    }
  }
}

// ---------------------------------------------------------------- sequential scan
// 64 persistent WGs; WG w owns H-cols [16w,16w+16); weights LDS-resident.
// Cross-WG h broadcast: fp16 payload, u64 agent-scope atomics, padded flags.
#define SCAN_LDS 155072
__global__ __launch_bounds__(256, 1) void k_scan(
    const float* __restrict__ h0g,  const float* __restrict__ Wg,
    const float* __restrict__ bg,   const float* __restrict__ Wr,
    const float* __restrict__ brv,  const float* __restrict__ lng_g,
    const float* __restrict__ lnb_g,const f16* __restrict__ z,
    f16* __restrict__ hid,          f16* __restrict__ hpub,
    unsigned* __restrict__ flags,   float* __restrict__ finalh) {
  extern __shared__ char smem[];
  f16*   Wlds = (f16*)smem;                 // 48 cols x 1048 f16
  f16*   hlds = (f16*)(smem + 100608);      // 16 rows x 1048 f16 (rows 8..15 zero)
  float* red  = (float*)(smem + 134144);    // 4 waves x 3 tiles x 64 lanes x 4
  float* lng  = (float*)(smem + 146432);
  float* lnb  = (float*)(smem + 150528);
  float* bia  = (float*)(smem + 154624);    // 192 B
  f16*   pub  = (f16*)(smem + 154816);      // 128 f16 staging (256 B)

  const int tid  = threadIdx.x;
  const int wg   = blockIdx.x;
  const int wave = tid >> 6, lane = tid & 63;
  const int r8   = tid >> 5, g32 = tid & 31;      // LN: 8 rows x 32 lanes
  const int rr   = (tid >> 4) & 7, cc = tid & 15; // 128-thread (row,col) ops

  // ---- setup: weights -> LDS fp16 (one-time)
  for (int i = tid; i < 48*1024; i += 256) {
    int c = i >> 10, k = i & 1023;
    float wv;
    if (c < 16)      wv = Wg[(size_t)k*2048 + wg*16 + c];
    else if (c < 32) wv = Wg[(size_t)k*2048 + 1024 + wg*16 + (c-16)];
    else             wv = Wr[(size_t)k*1024 + wg*16 + (c-32)];
    Wlds[c*1048 + k] = (f16)wv;
  }
  for (int i = tid; i < 1024; i += 256) { lng[i] = lng_g[i]; lnb[i] = lnb_g[i]; }
  if (tid < 48)
    bia[tid] = (tid < 16) ? bg[wg*16 + tid]
             : (tid < 32) ? bg[1024 + wg*16 + (tid-16)]
                          : brv[wg*16 + (tid-32)];
  for (int i = tid; i < 8*1048; i += 256) hlds[8*1048 + i] = (f16)0.f;
  __syncthreads();

  for (int t = 0; t <= NS; ++t) {
    // prefetch this step's z slice (plain cached loads, issued before the wait)
    f16 zreg = (f16)0.f;
    if (t < NS && tid < 128) zreg = z[(((size_t)t*64 + wg)*8 + rr)*16 + cc];

    if (t > 0) {
      if (tid < 64) {
        while (__hip_atomic_load(&flags[tid*16], __ATOMIC_RELAXED,
                                 __HIP_MEMORY_SCOPE_AGENT) < (unsigned)t) { }
      }
      __syncthreads();
    }

    // ---- Phase A: h_t -> hlds (fp16), redundant LN per WG
    if (t == 0) {
#pragma unroll
      for (int j = 0; j < 8; ++j) {
        f32x4 v = *(const f32x4*)(h0g + r8*1024 + (j*32 + g32)*4);
        int colb = j*128 + g32*4;
        f16x4 hv = { (f16)v[0], (f16)v[1], (f16)v[2], (f16)v[3] };
        *(f16x4*)(hlds + r8*1048 + colb) = hv;
      }
    } else {
      const u64* src = (const u64*)(hpub + ((t-1) & 1)*(8*1024));
      float vals[8][4];
      float sum = 0.f, sq = 0.f;
#pragma unroll
      for (int j = 0; j < 8; ++j) {
        u64 raw = __hip_atomic_load(src + r8*256 + j*32 + g32,
                                    __ATOMIC_RELAXED, __HIP_MEMORY_SCOPE_AGENT);
        f16x4 hv = __builtin_bit_cast(f16x4, raw);
#pragma unroll
        for (int e = 0; e < 4; ++e) {
          float v = (float)hv[e];
          vals[j][e] = v; sum += v; sq += v*v;
        }
      }
#pragma unroll
      for (int off = 16; off > 0; off >>= 1) {
        sum += __shfl_xor(sum, off, 32);
        sq  += __shfl_xor(sq,  off, 32);
      }
      float m  = sum * (1.f/1024.f);
      float va = sq  * (1.f/1024.f) - m*m;
      float rs = rsqrtf(va + 1e-5f);
#pragma unroll
      for (int j = 0; j < 8; ++j) {
        int colb = j*128 + g32*4;
        f16x4 hv;
#pragma unroll
        for (int e = 0; e < 4; ++e)
          hv[e] = (f16)((vals[j][e] - m)*rs*lng[colb+e] + lnb[colb+e]);
        *(f16x4*)(hlds + r8*1048 + colb) = hv;
      }
    }
    __syncthreads();

    // owner writes hiddens[t-1] (= post-LN h_t), vectorized u64
    if (t >= 1 && tid < 32) {
      int row = tid >> 2, ch = tid & 3;
      u64 v = *(const u64*)(hlds + row*1048 + wg*16 + ch*4);
      *(u64*)(hid + ((size_t)(t-1)*8 + row)*1024 + wg*16 + ch*4) = v;
    }
    if (t == NS) {
      if (tid < 128) finalh[rr*1024 + wg*16 + cc] = (float)hlds[rr*1048 + wg*16 + cc];
      break;
    }

    // ---- Phase B: [16x1024]x[1024x48] via MFMA, K split over 4 waves
    f32x4 acc0 = {0,0,0,0}, acc1 = {0,0,0,0}, acc2 = {0,0,0,0};
    {
      const char* hb = (const char*)hlds + (lane & 15)*2096;
      const char* w0 = (const char*)Wlds + ((lane & 15))*2096;
      const char* w1 = (const char*)Wlds + (16 + (lane & 15))*2096;
      const char* w2 = (const char*)Wlds + (32 + (lane & 15))*2096;
      int kbase = wave*256 + ((lane >> 4) << 3);
#pragma unroll
      for (int ks = 0; ks < 8; ++ks) {
        int kb = (kbase + ks*32) * 2;
        f16x8 af = *(const f16x8*)(hb + kb);
        f16x8 b0 = *(const f16x8*)(w0 + kb);
        f16x8 b1 = *(const f16x8*)(w1 + kb);
        f16x8 b2 = *(const f16x8*)(w2 + kb);
        acc0 = __builtin_amdgcn_mfma_f32_16x16x32_f16(af, b0, acc0, 0, 0, 0);
        acc1 = __builtin_amdgcn_mfma_f32_16x16x32_f16(af, b1, acc1, 0, 0, 0);
        acc2 = __builtin_amdgcn_mfma_f32_16x16x32_f16(af, b2, acc2, 0, 0, 0);
      }
    }
    *(f32x4*)(red + ((wave*3 + 0)*64 + lane)*4) = acc0;
    *(f32x4*)(red + ((wave*3 + 1)*64 + lane)*4) = acc1;
    *(f32x4*)(red + ((wave*3 + 2)*64 + lane)*4) = acc2;
    __syncthreads();

    // ---- Phase C: cross-wave reduce + gate math, stage slice in LDS
    if (tid < 128) {
      int li  = ((rr >> 2) << 4) + cc;
      int reg = rr & 3;
      float s0 = 0.f, s1 = 0.f, s2 = 0.f;
#pragma unroll
      for (int q = 0; q < 4; ++q) {
        s0 += red[((q*3 + 0)*64 + li)*4 + reg];
        s1 += red[((q*3 + 1)*64 + li)*4 + reg];
        s2 += red[((q*3 + 2)*64 + li)*4 + reg];
      }
      float gv = s0 + bia[cc];
      float gt = s1 + bia[16 + cc];
      float rc = s2 + bia[32 + cc];
      float gate = fsig(gv) * fsilu(gt);
      float nh   = gate*rc + (1.f - gate)*(float)zreg;
      pub[rr*16 + cc] = (f16)nh;
    }
    __syncthreads();

    // ---- publish slice (wave 0: 32 x u64 stores) then release flag (tid 0,
    // same wave -> release's vmcnt(0) covers the slice stores)
    if (tid < 32) {
      u64 v = ((const u64*)pub)[tid];
      int row = tid >> 2, ch = tid & 3;
      __hip_atomic_store((u64*)(hpub + (t & 1)*(8*1024)) + row*256 + (wg*16 + ch*4)/4,
                         v, __ATOMIC_RELAXED, __HIP_MEMORY_SCOPE_AGENT);
    }
    if (tid == 0)
      __hip_atomic_store(&flags[wg*16], (unsigned)(t+1),
                         __ATOMIC_RELEASE, __HIP_MEMORY_SCOPE_AGENT);
  }
}

// ---------------------------------------------------------------- launcher
extern "C" void kernel_launch(void* const* d_in, const int* in_sizes, int n_in,
                              void* d_out, int out_size, void* d_ws, size_t ws_size,
                              hipStream_t stream) {
  const float* x      = (const float*)d_in[0];
  const float* h0     = (const float*)d_in[1];
  const float* W_in   = (const float*)d_in[2];
  const float* b_in   = (const float*)d_in[3];
  const float* W_rec  = (const float*)d_in[4];
  const float* b_rec  = (const float*)d_in[5];
  const float* W_gate = (const float*)d_in[6];
  const float* b_gate = (const float*)d_in[7];
  const float* W_out  = (const float*)d_in[8];
  const float* b_out  = (const float*)d_in[9];
  const float* ln_g   = (const float*)d_in[10];
  const float* ln_b   = (const float*)d_in[11];
  float* out = (float*)d_out;

  char* ws = (char*)d_ws;
  f16*   x_f16  = (f16*)(ws);                         // 33,554,432 B
  f16*   Wt_in  = (f16*)(ws + 33554432);              //  6,291,456 B
  f16*   Wt_out = (f16*)(ws + 39845888);              //  2,097,152 B
  f16*   z      = (f16*)(ws + 41943040);              // 33,554,432 B
  f16*   hid    = (f16*)(ws + 75497472);              // 33,554,432 B
  f16*   hpub   = (f16*)(ws + 109051904);             //     32,768 B (2x8x1024 f16)
  unsigned* flg = (unsigned*)(ws + 109084672);        //      4,096 B (64 x 64B)

  hipMemsetAsync(flg, 0, 4096, stream);

  k_cvt_f16<<<2048, 256, 0, stream>>>(x, x_f16, NB*NS*NHID);
  { dim3 g(32, 96); k_transpose_cvt<<<g, 256, 0, stream>>>(W_in,  Wt_in,  1024, 3072); }
  { dim3 g(32, 32); k_transpose_cvt<<<g, 256, 0, stream>>>(W_out, Wt_out, 1024, 1024); }

  { dim3 g(128, 32); k_gemm1<<<g, 256, 0, stream>>>(x_f16, Wt_in, b_in, z); }

  hipFuncSetAttribute((const void*)k_scan, hipFuncAttributeMaxDynamicSharedMemorySize, SCAN_LDS);
  k_scan<<<NWG, 256, SCAN_LDS, stream>>>(h0, W_gate, b_gate, W_rec, b_rec,
                                         ln_g, ln_b, z, hid, hpub, flg,
                                         out + (size_t)NB*NS*NHID);

  { dim3 g(128, 32); k_gemm3<<<g, 256, 0, stream>>>(hid, Wt_out, b_out, out); }
}

// Round 4
// 8516.508 us; speedup vs baseline: 1.4918x; 1.1057x over previous
//
#include <hip/hip_runtime.h>
#include <stdint.h>
#include <stddef.h>

typedef _Float16 f16;
typedef __attribute__((ext_vector_type(8))) _Float16 f16x8;
typedef __attribute__((ext_vector_type(4))) _Float16 f16x4;
typedef __attribute__((ext_vector_type(4))) float     f32x4;
typedef unsigned long long u64;

#define NB 8
#define NS 2048
#define NHID 1024
#define NWG 64

__device__ __forceinline__ float fsig(float x)  { return 1.f/(1.f+__expf(-x)); }
__device__ __forceinline__ float fsilu(float x) { return x/(1.f+__expf(-x)); }

// ---------------------------------------------------------------- pre-kernels
__global__ __launch_bounds__(256) void k_cvt_f16(const float* __restrict__ in,
                                                 f16* __restrict__ out, int n) {
  int i = (blockIdx.x*blockDim.x + threadIdx.x)*4;
  int stride = gridDim.x*blockDim.x*4;
  for (; i < n; i += stride) {
    f32x4 v = *(const f32x4*)(in + i);
    f16x4 o = { (f16)v[0], (f16)v[1], (f16)v[2], (f16)v[3] };
    *(f16x4*)(out + i) = o;
  }
}

// W [K][N] f32 -> Wt [N][K] f16
__global__ __launch_bounds__(256) void k_transpose_cvt(const float* __restrict__ W,
                                                       f16* __restrict__ Wt,
                                                       int K, int N) {
  __shared__ float tile[32][33];
  int k0 = blockIdx.x*32, n0 = blockIdx.y*32;
  int tx = threadIdx.x & 31, ty = threadIdx.x >> 5;
  for (int i = ty; i < 32; i += 8) tile[i][tx] = W[(size_t)(k0+i)*N + n0 + tx];
  __syncthreads();
  for (int i = ty; i < 32; i += 8) Wt[(size_t)(n0+i)*K + k0 + tx] = (f16)tile[tx][i];
}

// ---------------------------------------------------------------- GEMM 1: z = silu(xW_u)*silu(xW_v)+xW_w
__global__ __launch_bounds__(256) void k_gemm1(const f16* __restrict__ A,
                                               const f16* __restrict__ Bt,
                                               const float* __restrict__ b_in,
                                               f16* __restrict__ z) {
  __shared__ f16 As[2][128*64];
  __shared__ f16 Bs[2][3][32*64];
  const int tid  = threadIdx.x;
  const int row0 = blockIdx.x * 128;
  const int j0   = blockIdx.y * 32;
  const int lane = tid & 63, wave = tid >> 6;
  const int wm = wave >> 1, wj = wave & 1;

  f32x4 acc[4][3];
  const f32x4 zv = {0.f,0.f,0.f,0.f};
#pragma unroll
  for (int m = 0; m < 4; ++m)
#pragma unroll
    for (int s = 0; s < 3; ++s) acc[m][s] = zv;

  f16x8 ar[4]; f16x8 br[3];

  auto loadT = [&](int kt) {
    int k0 = kt*64;
#pragma unroll
    for (int i = 0; i < 4; ++i) {
      int c = tid + i*256; int r = c >> 3;
      ar[i] = *(const f16x8*)(A + (size_t)(row0 + r)*1024 + k0 + (c & 7)*8);
    }
#pragma unroll
    for (int i = 0; i < 3; ++i) {
      int c = tid + i*256; int strip = c >> 8; int cc = c & 255; int r = cc >> 3;
      br[i] = *(const f16x8*)(Bt + (size_t)(strip*1024 + j0 + r)*1024 + k0 + (cc & 7)*8);
    }
  };
  auto writeT = [&](int buf) {
#pragma unroll
    for (int i = 0; i < 4; ++i) {
      int c = tid + i*256; int r = c >> 3; int kb = (c & 7)*16;
      *(f16x8*)((char*)As[buf] + r*128 + (kb ^ ((r & 7) << 4))) = ar[i];
    }
#pragma unroll
    for (int i = 0; i < 3; ++i) {
      int c = tid + i*256; int strip = c >> 8; int cc = c & 255; int r = cc >> 3; int kb = (cc & 7)*16;
      *(f16x8*)((char*)Bs[buf][strip] + r*128 + (kb ^ ((r & 7) << 4))) = br[i];
    }
  };
  auto compute = [&](int buf) {
    const char* Ab = (const char*)As[buf];
#pragma unroll
    for (int kk = 0; kk < 2; ++kk) {
      int kq = kk*64 + ((lane >> 4) << 4);
      f16x8 af[4];
#pragma unroll
      for (int mt = 0; mt < 4; ++mt) {
        int r = wm*64 + mt*16 + (lane & 15);
        af[mt] = *(const f16x8*)(Ab + r*128 + (kq ^ ((r & 7) << 4)));
      }
#pragma unroll
      for (int st = 0; st < 3; ++st) {
        int cB = wj*16 + (lane & 15);
        f16x8 bf = *(const f16x8*)((const char*)Bs[buf][st] + cB*128 + (kq ^ ((cB & 7) << 4)));
#pragma unroll
        for (int mt = 0; mt < 4; ++mt)
          acc[mt][st] = __builtin_amdgcn_mfma_f32_16x16x32_f16(af[mt], bf, acc[mt][st], 0, 0, 0);
      }
    }
  };

  loadT(0); writeT(0);
  __syncthreads();
  for (int kt = 0; kt < 16; ++kt) {
    int cur = kt & 1;
    if (kt + 1 < 16) loadT(kt+1);
    compute(cur);
    if (kt + 1 < 16) writeT(cur ^ 1);
    __syncthreads();
  }

  const int jc = j0 + wj*16 + (lane & 15);
  const float bu = b_in[jc], bv = b_in[1024 + jc], bw = b_in[2048 + jc];
#pragma unroll
  for (int mt = 0; mt < 4; ++mt) {
#pragma unroll
    for (int i = 0; i < 4; ++i) {
      int r = row0 + wm*64 + mt*16 + ((lane >> 4) << 2) + i;
      float u = acc[mt][0][i] + bu;
      float v = acc[mt][1][i] + bv;
      float w = acc[mt][2][i] + bw;
      float zz = fsilu(u)*fsilu(v) + w;
      int b_ = r >> 11, s_ = r & 2047;
      z[(((size_t)s_*64 + (jc >> 4))*8 + b_)*16 + (jc & 15)] = (f16)zz;
    }
  }
}

// ---------------------------------------------------------------- GEMM 3: out = hiddens @ W_out + b_out
__global__ __launch_bounds__(256) void k_gemm3(const f16* __restrict__ A,
                                               const f16* __restrict__ Bt,
                                               const float* __restrict__ b_out,
                                               float* __restrict__ out) {
  __shared__ f16 As[2][128*64];
  __shared__ f16 Bs[2][32*64];
  const int tid  = threadIdx.x;
  const int row0 = blockIdx.x * 128;
  const int n0   = blockIdx.y * 32;
  const int lane = tid & 63, wave = tid >> 6;
  const int wm = wave >> 1, wn = wave & 1;

  f32x4 acc[4];
  const f32x4 zv = {0.f,0.f,0.f,0.f};
#pragma unroll
  for (int m = 0; m < 4; ++m) acc[m] = zv;

  f16x8 ar[4]; f16x8 br1;

  auto loadT = [&](int kt) {
    int k0 = kt*64;
#pragma unroll
    for (int i = 0; i < 4; ++i) {
      int c = tid + i*256; int r = c >> 3;
      ar[i] = *(const f16x8*)(A + (size_t)(row0 + r)*1024 + k0 + (c & 7)*8);
    }
    { int c = tid; int r = c >> 3;
      br1 = *(const f16x8*)(Bt + (size_t)(n0 + r)*1024 + k0 + (c & 7)*8); }
  };
  auto writeT = [&](int buf) {
#pragma unroll
    for (int i = 0; i < 4; ++i) {
      int c = tid + i*256; int r = c >> 3; int kb = (c & 7)*16;
      *(f16x8*)((char*)As[buf] + r*128 + (kb ^ ((r & 7) << 4))) = ar[i];
    }
    { int c = tid; int r = c >> 3; int kb = (c & 7)*16;
      *(f16x8*)((char*)Bs[buf] + r*128 + (kb ^ ((r & 7) << 4))) = br1; }
  };
  auto compute = [&](int buf) {
    const char* Ab = (const char*)As[buf];
#pragma unroll
    for (int kk = 0; kk < 2; ++kk) {
      int kq = kk*64 + ((lane >> 4) << 4);
      int cB = wn*16 + (lane & 15);
      f16x8 bf = *(const f16x8*)((const char*)Bs[buf] + cB*128 + (kq ^ ((cB & 7) << 4)));
#pragma unroll
      for (int mt = 0; mt < 4; ++mt) {
        int r = wm*64 + mt*16 + (lane & 15);
        f16x8 af = *(const f16x8*)(Ab + r*128 + (kq ^ ((r & 7) << 4)));
        acc[mt] = __builtin_amdgcn_mfma_f32_16x16x32_f16(af, bf, acc[mt], 0, 0, 0);
      }
    }
  };

  loadT(0); writeT(0);
  __syncthreads();
  for (int kt = 0; kt < 16; ++kt) {
    int cur = kt & 1;
    if (kt + 1 < 16) loadT(kt+1);
    compute(cur);
    if (kt + 1 < 16) writeT(cur ^ 1);
    __syncthreads();
  }

  const int n = n0 + wn*16 + (lane & 15);
  const float bo = b_out[n];
#pragma unroll
  for (int mt = 0; mt < 4; ++mt) {
#pragma unroll
    for (int i = 0; i < 4; ++i) {
      int r = row0 + wm*64 + mt*16 + ((lane >> 4) << 2) + i;
      int s = r >> 3, b = r & 7;
      out[(size_t)b*(NS*NHID) + (size_t)s*NHID + n] = acc[mt][i] + bo;
    }
  }
}

// ---------------------------------------------------------------- sequential scan
// 64 persistent WGs; WG w owns H-cols [16w,16w+16); weights VGPR-resident.
// Cross-WG h broadcast: single-phase self-validating publish
//   u64 = {f16 v0 | f16 v1 | f16 v2 | u16 tag=t}, 44 words per WG slice,
//   relaxed agent atomics only (no flags, no release/acquire RTT chain).
#define SCAN_LDS 70848
__global__ __launch_bounds__(256, 1) void k_scan(
    const float* __restrict__ h0g,  const float* __restrict__ Wg,
    const float* __restrict__ bg,   const float* __restrict__ Wr,
    const float* __restrict__ brv,  const float* __restrict__ lng_g,
    const float* __restrict__ lnb_g,const f16* __restrict__ z,
    f16* __restrict__ hid,          u64* __restrict__ hpub,
    float* __restrict__ finalh) {
  extern __shared__ char smem[];
  f16*   hlds = (f16*)smem;                 // 16 x 1048 f16 (rows 8..15 zero) 33,536
  f16*   nhst = (f16*)(smem + 33536);       // 8 x 1024 f16 nh staging   16,384
  float* red  = (float*)(smem + 49920);     // 4 waves x 3 tiles x 64 x 4  12,288
  float* lng  = (float*)(smem + 62208);     // 4,096
  float* lnb  = (float*)(smem + 66304);     // 4,096
  float* bia  = (float*)(smem + 70400);     // 192
  f16*   pub  = (f16*)(smem + 70592);       // 128 f16 staging (256 B)

  const int tid  = threadIdx.x;
  const int wg   = blockIdx.x;
  const int wave = tid >> 6, lane = tid & 63;
  const int r8   = tid >> 5, g32 = tid & 31;      // LN: 8 rows x 32 lanes
  const int rr   = (tid >> 4) & 7, cc = tid & 15; // 128-thread (row,col) ops

  // ---- setup: per-wave MFMA B-fragments (weights) -> VGPRs, one-time
  f16x8 wf0[8], wf1[8], wf2[8];
  {
    const int cB = wg*16 + (lane & 15);
    const int kq = (lane >> 4) << 3;
#pragma unroll
    for (int ks = 0; ks < 8; ++ks) {
      int k = wave*256 + ks*32 + kq;
      f16x8 a, b, c;
#pragma unroll
      for (int e = 0; e < 8; ++e) {
        a[e] = (f16)Wg[(size_t)(k+e)*2048 + cB];
        b[e] = (f16)Wg[(size_t)(k+e)*2048 + 1024 + cB];
        c[e] = (f16)Wr[(size_t)(k+e)*1024 + cB];
      }
      wf0[ks] = a; wf1[ks] = b; wf2[ks] = c;
    }
  }
  for (int i = tid; i < 1024; i += 256) { lng[i] = lng_g[i]; lnb[i] = lnb_g[i]; }
  if (tid < 48)
    bia[tid] = (tid < 16) ? bg[wg*16 + tid]
             : (tid < 32) ? bg[1024 + wg*16 + (tid-16)]
                          : brv[wg*16 + (tid-32)];
  for (int i = tid; i < 8*1048; i += 256) hlds[8*1048 + i] = (f16)0.f;
  __syncthreads();

  for (int t = 0; t <= NS; ++t) {
    // prefetch this step's z slice (plain cached loads, issued before the poll)
    f16 zreg = (f16)0.f;
    if (t < NS && tid < 128) zreg = z[(((size_t)t*64 + wg)*8 + rr)*16 + cc];

    // ---- Phase A: obtain h-state
    if (t == 0) {
#pragma unroll
      for (int j = 0; j < 8; ++j) {
        f32x4 v = *(const f32x4*)(h0g + r8*1024 + (j*32 + g32)*4);
        int colb = j*128 + g32*4;
        f16x4 hv = { (f16)v[0], (f16)v[1], (f16)v[2], (f16)v[3] };
        *(f16x4*)(hlds + r8*1048 + colb) = hv;
      }
      __syncthreads();
    } else {
      // poll self-validating payload (tag == t in every u64)
      const u64* src = hpub + (size_t)(t & 1)*2816;
      u64 got[11];
      unsigned ok = 0;
      while (!ok) {
        ok = 1;
#pragma unroll
        for (int i = 0; i < 11; ++i) {
          got[i] = __hip_atomic_load(src + i*256 + tid,
                                     __ATOMIC_RELAXED, __HIP_MEMORY_SCOPE_AGENT);
          ok &= (unsigned)((unsigned)(got[i] >> 48) == (unsigned)t);
        }
      }
      // unpack 3 f16 per word into nh staging
#pragma unroll
      for (int i = 0; i < 11; ++i) {
        int gidx = i*256 + tid;
        int wgI = gidx / 44;
        int slot = gidx - wgI*44;
        if (slot < 43) {
          int s0 = slot*3;
          u64 g = got[i];
#pragma unroll
          for (int e = 0; e < 3; ++e) {
            int s = s0 + e;
            if (s < 128) {
              unsigned short hb = (unsigned short)(g >> (16*e));
              nhst[((s >> 4))*1024 + wgI*16 + (s & 15)] = __builtin_bit_cast(f16, hb);
            }
          }
        }
      }
      __syncthreads();

      // redundant LN: row r8, 32 lanes
      float sum = 0.f, sq = 0.f;
#pragma unroll
      for (int j = 0; j < 8; ++j) {
        f16x4 hv = *(const f16x4*)(nhst + r8*1024 + (j*32 + g32)*4);
#pragma unroll
        for (int e = 0; e < 4; ++e) { float v = (float)hv[e]; sum += v; sq += v*v; }
      }
#pragma unroll
      for (int off = 16; off > 0; off >>= 1) {
        sum += __shfl_xor(sum, off, 32);
        sq  += __shfl_xor(sq,  off, 32);
      }
      float m  = sum * (1.f/1024.f);
      float va = sq  * (1.f/1024.f) - m*m;
      float rs = rsqrtf(va + 1e-5f);
#pragma unroll
      for (int j = 0; j < 8; ++j) {
        int colb = (j*32 + g32)*4;
        f16x4 hv = *(const f16x4*)(nhst + r8*1024 + colb);
        f16x4 o;
#pragma unroll
        for (int e = 0; e < 4; ++e)
          o[e] = (f16)(((float)hv[e] - m)*rs*lng[colb+e] + lnb[colb+e]);
        *(f16x4*)(hlds + r8*1048 + colb) = o;
      }
      __syncthreads();
    }

    // owner writes hiddens[t-1] (= post-LN h_t), vectorized u64
    if (t >= 1 && tid < 32) {
      int row = tid >> 2, ch = tid & 3;
      u64 v = *(const u64*)(hlds + row*1048 + wg*16 + ch*4);
      *(u64*)(hid + ((size_t)(t-1)*8 + row)*1024 + wg*16 + ch*4) = v;
    }
    if (t == NS) {
      if (tid < 128) finalh[rr*1024 + wg*16 + cc] = (float)hlds[rr*1048 + wg*16 + cc];
      break;
    }

    // ---- Phase B: [16x1024]x[1024x48] MFMA, K split over 4 waves, B from VGPRs
    f32x4 acc0 = {0,0,0,0}, acc1 = {0,0,0,0}, acc2 = {0,0,0,0};
    {
      const char* hb = (const char*)hlds + (lane & 15)*2096;
      const int kbyte0 = (wave*256 + ((lane >> 4) << 3))*2;
#pragma unroll
      for (int ks = 0; ks < 8; ++ks) {
        f16x8 af = *(const f16x8*)(hb + kbyte0 + ks*64);
        acc0 = __builtin_amdgcn_mfma_f32_16x16x32_f16(af, wf0[ks], acc0, 0, 0, 0);
        acc1 = __builtin_amdgcn_mfma_f32_16x16x32_f16(af, wf1[ks], acc1, 0, 0, 0);
        acc2 = __builtin_amdgcn_mfma_f32_16x16x32_f16(af, wf2[ks], acc2, 0, 0, 0);
      }
    }
    *(f32x4*)(red + ((wave*3 + 0)*64 + lane)*4) = acc0;
    *(f32x4*)(red + ((wave*3 + 1)*64 + lane)*4) = acc1;
    *(f32x4*)(red + ((wave*3 + 2)*64 + lane)*4) = acc2;
    __syncthreads();

    // ---- Phase C: cross-wave reduce + gate math, stage slice in LDS
    if (tid < 128) {
      int li  = ((rr >> 2) << 4) + cc;
      int reg = rr & 3;
      float s0 = 0.f, s1 = 0.f, s2 = 0.f;
#pragma unroll
      for (int q = 0; q < 4; ++q) {
        s0 += red[((q*3 + 0)*64 + li)*4 + reg];
        s1 += red[((q*3 + 1)*64 + li)*4 + reg];
        s2 += red[((q*3 + 2)*64 + li)*4 + reg];
      }
      float gv = s0 + bia[cc];
      float gt = s1 + bia[16 + cc];
      float rc = s2 + bia[32 + cc];
      float gate = fsig(gv) * fsilu(gt);
      float nh   = gate*rc + (1.f - gate)*(float)zreg;
      pub[rr*16 + cc] = (f16)nh;
    }
    __syncthreads();

    // ---- publish: 44 tagged u64 words, relaxed agent atomics, fire-and-forget
    if (tid < 44) {
      int s0 = tid*3;
      unsigned short b0 = (s0     < 128) ? __builtin_bit_cast(unsigned short, pub[s0])     : (unsigned short)0;
      unsigned short b1 = (s0 + 1 < 128) ? __builtin_bit_cast(unsigned short, pub[s0 + 1]) : (unsigned short)0;
      unsigned short b2 = (s0 + 2 < 128) ? __builtin_bit_cast(unsigned short, pub[s0 + 2]) : (unsigned short)0;
      u64 v = (u64)b0 | ((u64)b1 << 16) | ((u64)b2 << 32) | ((u64)(unsigned)(t + 1) << 48);
      __hip_atomic_store(hpub + (size_t)((t + 1) & 1)*2816 + wg*44 + tid, v,
                         __ATOMIC_RELAXED, __HIP_MEMORY_SCOPE_AGENT);
    }
  }
}

// ---------------------------------------------------------------- launcher
extern "C" void kernel_launch(void* const* d_in, const int* in_sizes, int n_in,
                              void* d_out, int out_size, void* d_ws, size_t ws_size,
                              hipStream_t stream) {
  const float* x      = (const float*)d_in[0];
  const float* h0     = (const float*)d_in[1];
  const float* W_in   = (const float*)d_in[2];
  const float* b_in   = (const float*)d_in[3];
  const float* W_rec  = (const float*)d_in[4];
  const float* b_rec  = (const float*)d_in[5];
  const float* W_gate = (const float*)d_in[6];
  const float* b_gate = (const float*)d_in[7];
  const float* W_out  = (const float*)d_in[8];
  const float* b_out  = (const float*)d_in[9];
  const float* ln_g   = (const float*)d_in[10];
  const float* ln_b   = (const float*)d_in[11];
  float* out = (float*)d_out;

  char* ws = (char*)d_ws;
  f16*   x_f16  = (f16*)(ws);                         // 33,554,432 B
  f16*   Wt_in  = (f16*)(ws + 33554432);              //  6,291,456 B
  f16*   Wt_out = (f16*)(ws + 39845888);              //  2,097,152 B
  f16*   z      = (f16*)(ws + 41943040);              // 33,554,432 B
  f16*   hid    = (f16*)(ws + 75497472);              // 33,554,432 B
  u64*   hpub   = (u64*)(ws + 109051904);             //     45,056 B (2 x 2816 u64)

  k_cvt_f16<<<2048, 256, 0, stream>>>(x, x_f16, NB*NS*NHID);
  { dim3 g(32, 96); k_transpose_cvt<<<g, 256, 0, stream>>>(W_in,  Wt_in,  1024, 3072); }
  { dim3 g(32, 32); k_transpose_cvt<<<g, 256, 0, stream>>>(W_out, Wt_out, 1024, 1024); }

  { dim3 g(128, 32); k_gemm1<<<g, 256, 0, stream>>>(x_f16, Wt_in, b_in, z); }

  hipFuncSetAttribute((const void*)k_scan, hipFuncAttributeMaxDynamicSharedMemorySize, SCAN_LDS);
  k_scan<<<NWG, 256, SCAN_LDS, stream>>>(h0, W_gate, b_gate, W_rec, b_rec,
                                         ln_g, ln_b, z, hid, hpub,
                                         out + (size_t)NB*NS*NHID);

  { dim3 g(128, 32); k_gemm3<<<g, 256, 0, stream>>>(hid, Wt_out, b_out, out); }
}

// Round 5
// 7113.240 us; speedup vs baseline: 1.7861x; 1.1973x over previous
//
#include <hip/hip_runtime.h>
#include <stdint.h>
#include <stddef.h>

typedef _Float16 f16;
typedef __attribute__((ext_vector_type(8))) _Float16 f16x8;
typedef __attribute__((ext_vector_type(4))) _Float16 f16x4;
typedef __attribute__((ext_vector_type(4))) float     f32x4;
typedef __attribute__((ext_vector_type(2))) float     f32x2;
typedef unsigned long long u64;

#define NB 8
#define NS 2048
#define NHID 1024
#define NWG 64

__device__ __forceinline__ float fsig(float x)  { return 1.f/(1.f+__expf(-x)); }
__device__ __forceinline__ float fsilu(float x) { return x/(1.f+__expf(-x)); }

// ---------------------------------------------------------------- pre-kernels
__global__ __launch_bounds__(256) void k_cvt_f16(const float* __restrict__ in,
                                                 f16* __restrict__ out, int n) {
  int i = (blockIdx.x*blockDim.x + threadIdx.x)*4;
  int stride = gridDim.x*blockDim.x*4;
  for (; i < n; i += stride) {
    f32x4 v = *(const f32x4*)(in + i);
    f16x4 o = { (f16)v[0], (f16)v[1], (f16)v[2], (f16)v[3] };
    *(f16x4*)(out + i) = o;
  }
}

// W [K][N] f32 -> Wt [N][K] f16
__global__ __launch_bounds__(256) void k_transpose_cvt(const float* __restrict__ W,
                                                       f16* __restrict__ Wt,
                                                       int K, int N) {
  __shared__ float tile[32][33];
  int k0 = blockIdx.x*32, n0 = blockIdx.y*32;
  int tx = threadIdx.x & 31, ty = threadIdx.x >> 5;
  for (int i = ty; i < 32; i += 8) tile[i][tx] = W[(size_t)(k0+i)*N + n0 + tx];
  __syncthreads();
  for (int i = ty; i < 32; i += 8) Wt[(size_t)(n0+i)*K + k0 + tx] = (f16)tile[tx][i];
}

// ---------------------------------------------------------------- GEMM 1: z = silu(xW_u)*silu(xW_v)+xW_w
__global__ __launch_bounds__(256) void k_gemm1(const f16* __restrict__ A,
                                               const f16* __restrict__ Bt,
                                               const float* __restrict__ b_in,
                                               f16* __restrict__ z) {
  __shared__ f16 As[2][128*64];
  __shared__ f16 Bs[2][3][32*64];
  const int tid  = threadIdx.x;
  const int row0 = blockIdx.x * 128;
  const int j0   = blockIdx.y * 32;
  const int lane = tid & 63, wave = tid >> 6;
  const int wm = wave >> 1, wj = wave & 1;

  f32x4 acc[4][3];
  const f32x4 zv = {0.f,0.f,0.f,0.f};
#pragma unroll
  for (int m = 0; m < 4; ++m)
#pragma unroll
    for (int s = 0; s < 3; ++s) acc[m][s] = zv;

  f16x8 ar[4]; f16x8 br[3];

  auto loadT = [&](int kt) {
    int k0 = kt*64;
#pragma unroll
    for (int i = 0; i < 4; ++i) {
      int c = tid + i*256; int r = c >> 3;
      ar[i] = *(const f16x8*)(A + (size_t)(row0 + r)*1024 + k0 + (c & 7)*8);
    }
#pragma unroll
    for (int i = 0; i < 3; ++i) {
      int c = tid + i*256; int strip = c >> 8; int cc = c & 255; int r = cc >> 3;
      br[i] = *(const f16x8*)(Bt + (size_t)(strip*1024 + j0 + r)*1024 + k0 + (cc & 7)*8);
    }
  };
  auto writeT = [&](int buf) {
#pragma unroll
    for (int i = 0; i < 4; ++i) {
      int c = tid + i*256; int r = c >> 3; int kb = (c & 7)*16;
      *(f16x8*)((char*)As[buf] + r*128 + (kb ^ ((r & 7) << 4))) = ar[i];
    }
#pragma unroll
    for (int i = 0; i < 3; ++i) {
      int c = tid + i*256; int strip = c >> 8; int cc = c & 255; int r = cc >> 3; int kb = (cc & 7)*16;
      *(f16x8*)((char*)Bs[buf][strip] + r*128 + (kb ^ ((r & 7) << 4))) = br[i];
    }
  };
  auto compute = [&](int buf) {
    const char* Ab = (const char*)As[buf];
#pragma unroll
    for (int kk = 0; kk < 2; ++kk) {
      int kq = kk*64 + ((lane >> 4) << 4);
      f16x8 af[4];
#pragma unroll
      for (int mt = 0; mt < 4; ++mt) {
        int r = wm*64 + mt*16 + (lane & 15);
        af[mt] = *(const f16x8*)(Ab + r*128 + (kq ^ ((r & 7) << 4)));
      }
#pragma unroll
      for (int st = 0; st < 3; ++st) {
        int cB = wj*16 + (lane & 15);
        f16x8 bf = *(const f16x8*)((const char*)Bs[buf][st] + cB*128 + (kq ^ ((cB & 7) << 4)));
#pragma unroll
        for (int mt = 0; mt < 4; ++mt)
          acc[mt][st] = __builtin_amdgcn_mfma_f32_16x16x32_f16(af[mt], bf, acc[mt][st], 0, 0, 0);
      }
    }
  };

  loadT(0); writeT(0);
  __syncthreads();
  for (int kt = 0; kt < 16; ++kt) {
    int cur = kt & 1;
    if (kt + 1 < 16) loadT(kt+1);
    compute(cur);
    if (kt + 1 < 16) writeT(cur ^ 1);
    __syncthreads();
  }

  const int jc = j0 + wj*16 + (lane & 15);
  const float bu = b_in[jc], bv = b_in[1024 + jc], bw = b_in[2048 + jc];
#pragma unroll
  for (int mt = 0; mt < 4; ++mt) {
#pragma unroll
    for (int i = 0; i < 4; ++i) {
      int r = row0 + wm*64 + mt*16 + ((lane >> 4) << 2) + i;
      float u = acc[mt][0][i] + bu;
      float v = acc[mt][1][i] + bv;
      float w = acc[mt][2][i] + bw;
      float zz = fsilu(u)*fsilu(v) + w;
      int b_ = r >> 11, s_ = r & 2047;
      z[(((size_t)s_*64 + (jc >> 4))*8 + b_)*16 + (jc & 15)] = (f16)zz;
    }
  }
}

// ---------------------------------------------------------------- GEMM 3: out = hiddens @ W_out + b_out
__global__ __launch_bounds__(256) void k_gemm3(const f16* __restrict__ A,
                                               const f16* __restrict__ Bt,
                                               const float* __restrict__ b_out,
                                               float* __restrict__ out) {
  __shared__ f16 As[2][128*64];
  __shared__ f16 Bs[2][32*64];
  const int tid  = threadIdx.x;
  const int row0 = blockIdx.x * 128;
  const int n0   = blockIdx.y * 32;
  const int lane = tid & 63, wave = tid >> 6;
  const int wm = wave >> 1, wn = wave & 1;

  f32x4 acc[4];
  const f32x4 zv = {0.f,0.f,0.f,0.f};
#pragma unroll
  for (int m = 0; m < 4; ++m) acc[m] = zv;

  f16x8 ar[4]; f16x8 br1;

  auto loadT = [&](int kt) {
    int k0 = kt*64;
#pragma unroll
    for (int i = 0; i < 4; ++i) {
      int c = tid + i*256; int r = c >> 3;
      ar[i] = *(const f16x8*)(A + (size_t)(row0 + r)*1024 + k0 + (c & 7)*8);
    }
    { int c = tid; int r = c >> 3;
      br1 = *(const f16x8*)(Bt + (size_t)(n0 + r)*1024 + k0 + (c & 7)*8); }
  };
  auto writeT = [&](int buf) {
#pragma unroll
    for (int i = 0; i < 4; ++i) {
      int c = tid + i*256; int r = c >> 3; int kb = (c & 7)*16;
      *(f16x8*)((char*)As[buf] + r*128 + (kb ^ ((r & 7) << 4))) = ar[i];
    }
    { int c = tid; int r = c >> 3; int kb = (c & 7)*16;
      *(f16x8*)((char*)Bs[buf] + r*128 + (kb ^ ((r & 7) << 4))) = br1; }
  };
  auto compute = [&](int buf) {
    const char* Ab = (const char*)As[buf];
#pragma unroll
    for (int kk = 0; kk < 2; ++kk) {
      int kq = kk*64 + ((lane >> 4) << 4);
      int cB = wn*16 + (lane & 15);
      f16x8 bf = *(const f16x8*)((const char*)Bs[buf] + cB*128 + (kq ^ ((cB & 7) << 4)));
#pragma unroll
      for (int mt = 0; mt < 4; ++mt) {
        int r = wm*64 + mt*16 + (lane & 15);
        f16x8 af = *(const f16x8*)(Ab + r*128 + (kq ^ ((r & 7) << 4)));
        acc[mt] = __builtin_amdgcn_mfma_f32_16x16x32_f16(af, bf, acc[mt], 0, 0, 0);
      }
    }
  };

  loadT(0); writeT(0);
  __syncthreads();
  for (int kt = 0; kt < 16; ++kt) {
    int cur = kt & 1;
    if (kt + 1 < 16) loadT(kt+1);
    compute(cur);
    if (kt + 1 < 16) writeT(cur ^ 1);
    __syncthreads();
  }

  const int n = n0 + wn*16 + (lane & 15);
  const float bo = b_out[n];
#pragma unroll
  for (int mt = 0; mt < 4; ++mt) {
#pragma unroll
    for (int i = 0; i < 4; ++i) {
      int r = row0 + wm*64 + mt*16 + ((lane >> 4) << 2) + i;
      int s = r >> 3, b = r & 7;
      out[(size_t)b*(NS*NHID) + (size_t)s*NHID + n] = acc[mt][i] + bo;
    }
  }
}

// ---------------------------------------------------------------- sequential scan
// 64 persistent WGs; WG w owns H-cols [16w,16w+16); weights VGPR-resident.
// Publish word = {f16 col2p | f16 col2p+1 | u32 tag}, 64 words/WG, 4096/buffer.
// Consumer thread T polls words g=i*256+T (i<16): all share (row,colpair) ->
// register-resident LN partials, conflict-free b32 unpack of NORMALIZED h.
#define SCAN_LDS 54208
__global__ __launch_bounds__(256, 1) void k_scan(
    const float* __restrict__ h0g,  const float* __restrict__ Wg,
    const float* __restrict__ bg,   const float* __restrict__ Wr,
    const float* __restrict__ brv,  const float* __restrict__ lng_g,
    const float* __restrict__ lnb_g,const f16* __restrict__ z,
    f16* __restrict__ hid,          u64* __restrict__ hpub,
    float* __restrict__ finalh) {
  extern __shared__ char smem[];
  f16*   hlds = (f16*)smem;                 // 16 x 1048 f16 (rows 8..15 zero) 33,536
  float* redw = (float*)(smem + 33536);     // phase-B acc dump / LN partials 12,288
  f32x2* gb   = (f32x2*)(smem + 45824);     // {gamma,beta}[1024]              8,192
  float* bia  = (float*)(smem + 54016);     // 192

  const int tid  = threadIdx.x;
  const int wg   = blockIdx.x;
  const int wave = tid >> 6, lane = tid & 63;
  const int r8   = tid >> 5, g32 = tid & 31;      // t==0 path: 8 rows x 32 lanes
  const int rr   = (tid >> 4) & 7, cc = tid & 15; // 128-thread (row,col) ops
  const int rL   = tid & 7;                        // LN row owned by this thread
  const int c2L  = (tid & 63) >> 3;                // LN colpair

  // ---- setup: per-wave MFMA B-fragments (weights) -> VGPRs, one-time
  f16x8 wf0[8], wf1[8], wf2[8];
  {
    const int cB = wg*16 + (lane & 15);
    const int kq = (lane >> 4) << 3;
#pragma unroll
    for (int ks = 0; ks < 8; ++ks) {
      int k = wave*256 + ks*32 + kq;
      f16x8 a, b, c;
#pragma unroll
      for (int e = 0; e < 8; ++e) {
        a[e] = (f16)Wg[(size_t)(k+e)*2048 + cB];
        b[e] = (f16)Wg[(size_t)(k+e)*2048 + 1024 + cB];
        c[e] = (f16)Wr[(size_t)(k+e)*1024 + cB];
      }
      wf0[ks] = a; wf1[ks] = b; wf2[ks] = c;
    }
  }
  for (int i = tid; i < 1024; i += 256) { f32x2 p = { lng_g[i], lnb_g[i] }; gb[i] = p; }
  if (tid < 48)
    bia[tid] = (tid < 16) ? bg[wg*16 + tid]
             : (tid < 32) ? bg[1024 + wg*16 + (tid-16)]
                          : brv[wg*16 + (tid-32)];
  for (int i = tid; i < 8*1048; i += 256) hlds[8*1048 + i] = (f16)0.f;
  __syncthreads();

  for (int t = 0; t <= NS; ++t) {
    // prefetch this step's z slice (plain cached loads, issued before the poll)
    f16 zreg = (f16)0.f;
    if (t < NS && tid < 128) zreg = z[(((size_t)t*64 + wg)*8 + rr)*16 + cc];

    // ---- Phase A: obtain h-state (poll + register LN + conflict-free unpack)
    if (t == 0) {
#pragma unroll
      for (int j = 0; j < 8; ++j) {
        f32x4 v = *(const f32x4*)(h0g + r8*1024 + (j*32 + g32)*4);
        int colb = j*128 + g32*4;
        f16x4 hv = { (f16)v[0], (f16)v[1], (f16)v[2], (f16)v[3] };
        *(f16x4*)(hlds + r8*1048 + colb) = hv;
      }
      __syncthreads();
    } else {
      const u64* src = hpub + (size_t)(t & 1)*4096;
      u64 got[16];
      for (;;) {
        unsigned ok = 1;
#pragma unroll
        for (int i = 0; i < 16; ++i) {
          got[i] = __hip_atomic_load(src + i*256 + tid,
                                     __ATOMIC_RELAXED, __HIP_MEMORY_SCOPE_AGENT);
          ok &= (unsigned)((unsigned)(got[i] >> 32) == (unsigned)t);
        }
        if (ok) break;
      }
      // register LN partials: this thread's 32 values all lie in row rL
      float vals[32];
      float sum = 0.f, sq = 0.f;
#pragma unroll
      for (int i = 0; i < 16; ++i) {
        unsigned lo = (unsigned)got[i];
        float va = (float)__builtin_bit_cast(f16, (unsigned short)(lo & 0xffff));
        float vb = (float)__builtin_bit_cast(f16, (unsigned short)(lo >> 16));
        vals[2*i] = va; vals[2*i+1] = vb;
        sum += va + vb; sq += va*va + vb*vb;
      }
      // combine the 8 lanes per row within the wave (lanes differ in bits 3..5)
#pragma unroll
      for (int off = 8; off <= 32; off <<= 1) {
        sum += __shfl_xor(sum, off, 64);
        sq  += __shfl_xor(sq,  off, 64);
      }
      if (lane < 8) { f32x2 p = { sum, sq }; ((f32x2*)redw)[wave*8 + lane] = p; }
      __syncthreads();
      float s4 = 0.f, q4 = 0.f;
#pragma unroll
      for (int w2 = 0; w2 < 4; ++w2) {
        f32x2 p = ((const f32x2*)redw)[w2*8 + rL];
        s4 += p[0]; q4 += p[1];
      }
      float m  = s4 * (1.f/1024.f);
      float va = q4 * (1.f/1024.f) - m*m;
      float rs = rsqrtf(va + 1e-5f);
      // normalize in registers, write 16 conflict-free b32 into hlds
#pragma unroll
      for (int i = 0; i < 16; ++i) {
        int wgI = i*4 + wave;
        int col = wgI*16 + c2L*2;
        f32x4 gg = *(const f32x4*)(gb + col);   // {g0,b0,g1,b1}
        float h0n = (vals[2*i]   - m)*rs*gg[0] + gg[1];
        float h1n = (vals[2*i+1] - m)*rs*gg[2] + gg[3];
        unsigned w32 = (unsigned)__builtin_bit_cast(unsigned short, (f16)h0n)
                     | ((unsigned)__builtin_bit_cast(unsigned short, (f16)h1n) << 16);
        *(unsigned*)((char*)hlds + rL*2096 + col*2) = w32;
      }
      __syncthreads();
    }

    // owner writes hiddens[t-1] (= post-LN h_t), vectorized u64
    if (t >= 1 && tid < 32) {
      int row = tid >> 2, ch = tid & 3;
      u64 v = *(const u64*)(hlds + row*1048 + wg*16 + ch*4);
      *(u64*)(hid + ((size_t)(t-1)*8 + row)*1024 + wg*16 + ch*4) = v;
    }
    if (t == NS) {
      if (tid < 128) finalh[rr*1024 + wg*16 + cc] = (float)hlds[rr*1048 + wg*16 + cc];
      break;
    }

    // ---- Phase B: [16x1024]x[1024x48] MFMA, K split over 4 waves, B from VGPRs
    f32x4 acc0 = {0,0,0,0}, acc1 = {0,0,0,0}, acc2 = {0,0,0,0};
    {
      const char* hb = (const char*)hlds + (lane & 15)*2096;
      const int kbyte0 = (wave*256 + ((lane >> 4) << 3))*2;
#pragma unroll
      for (int ks = 0; ks < 8; ++ks) {
        f16x8 af = *(const f16x8*)(hb + kbyte0 + ks*64);
        acc0 = __builtin_amdgcn_mfma_f32_16x16x32_f16(af, wf0[ks], acc0, 0, 0, 0);
        acc1 = __builtin_amdgcn_mfma_f32_16x16x32_f16(af, wf1[ks], acc1, 0, 0, 0);
        acc2 = __builtin_amdgcn_mfma_f32_16x16x32_f16(af, wf2[ks], acc2, 0, 0, 0);
      }
    }
    *(f32x4*)(redw + ((wave*3 + 0)*64 + lane)*4) = acc0;
    *(f32x4*)(redw + ((wave*3 + 1)*64 + lane)*4) = acc1;
    *(f32x4*)(redw + ((wave*3 + 2)*64 + lane)*4) = acc2;
    __syncthreads();

    // ---- Phase C: cross-wave reduce + gate math + direct shfl-paired publish
    if (tid < 128) {
      int li  = ((rr >> 2) << 4) + cc;
      int reg = rr & 3;
      float s0 = 0.f, s1 = 0.f, s2 = 0.f;
#pragma unroll
      for (int q = 0; q < 4; ++q) {
        s0 += redw[((q*3 + 0)*64 + li)*4 + reg];
        s1 += redw[((q*3 + 1)*64 + li)*4 + reg];
        s2 += redw[((q*3 + 2)*64 + li)*4 + reg];
      }
      float gv = s0 + bia[cc];
      float gt = s1 + bia[16 + cc];
      float rc = s2 + bia[32 + cc];
      float gate = fsig(gv) * fsilu(gt);
      float nh   = gate*rc + (1.f - gate)*(float)zreg;
      float nh_hi = __shfl_xor(nh, 1, 64);
      if ((cc & 1) == 0) {
        u64 v = (u64)__builtin_bit_cast(unsigned short, (f16)nh)
              | ((u64)__builtin_bit_cast(unsigned short, (f16)nh_hi) << 16)
              | ((u64)(unsigned)(t + 1) << 32);
        __hip_atomic_store(hpub + (size_t)((t + 1) & 1)*4096 + wg*64 + (cc >> 1)*8 + rr,
                           v, __ATOMIC_RELAXED, __HIP_MEMORY_SCOPE_AGENT);
      }
    }
    // no barrier here: next poll gates on ALL WGs' publishes; redw/hlds reuse
    // is protected by the poll + the two barriers inside Phase A.
  }
}

// ---------------------------------------------------------------- launcher
extern "C" void kernel_launch(void* const* d_in, const int* in_sizes, int n_in,
                              void* d_out, int out_size, void* d_ws, size_t ws_size,
                              hipStream_t stream) {
  const float* x      = (const float*)d_in[0];
  const float* h0     = (const float*)d_in[1];
  const float* W_in   = (const float*)d_in[2];
  const float* b_in   = (const float*)d_in[3];
  const float* W_rec  = (const float*)d_in[4];
  const float* b_rec  = (const float*)d_in[5];
  const float* W_gate = (const float*)d_in[6];
  const float* b_gate = (const float*)d_in[7];
  const float* W_out  = (const float*)d_in[8];
  const float* b_out  = (const float*)d_in[9];
  const float* ln_g   = (const float*)d_in[10];
  const float* ln_b   = (const float*)d_in[11];
  float* out = (float*)d_out;

  char* ws = (char*)d_ws;
  f16*   x_f16  = (f16*)(ws);                         // 33,554,432 B
  f16*   Wt_in  = (f16*)(ws + 33554432);              //  6,291,456 B
  f16*   Wt_out = (f16*)(ws + 39845888);              //  2,097,152 B
  f16*   z      = (f16*)(ws + 41943040);              // 33,554,432 B
  f16*   hid    = (f16*)(ws + 75497472);              // 33,554,432 B
  u64*   hpub   = (u64*)(ws + 109051904);             //     65,536 B (2 x 4096 u64)

  k_cvt_f16<<<2048, 256, 0, stream>>>(x, x_f16, NB*NS*NHID);
  { dim3 g(32, 96); k_transpose_cvt<<<g, 256, 0, stream>>>(W_in,  Wt_in,  1024, 3072); }
  { dim3 g(32, 32); k_transpose_cvt<<<g, 256, 0, stream>>>(W_out, Wt_out, 1024, 1024); }

  { dim3 g(128, 32); k_gemm1<<<g, 256, 0, stream>>>(x_f16, Wt_in, b_in, z); }

  hipFuncSetAttribute((const void*)k_scan, hipFuncAttributeMaxDynamicSharedMemorySize, SCAN_LDS);
  k_scan<<<NWG, 256, SCAN_LDS, stream>>>(h0, W_gate, b_gate, W_rec, b_rec,
                                         ln_g, ln_b, z, hid, hpub,
                                         out + (size_t)NB*NS*NHID);

  { dim3 g(128, 32); k_gemm3<<<g, 256, 0, stream>>>(hid, Wt_out, b_out, out); }
}